// Round 1
// baseline (3616.379 us; speedup 1.0000x reference)
//
#include <hip/hip_runtime.h>

#define NN 100000
#define NE 1600000
// ws layout (floats): r_out[NN] | r_in[NN] | A[NN*64] | B[NN*64] | C[NN*16] | D[NN*16]
// total = 162*NN floats = 64.8 MB

__global__ __launch_bounds__(256) void k_deg(const int* __restrict__ src,
                                             const int* __restrict__ dst,
                                             float* __restrict__ deg_out,
                                             float* __restrict__ deg_in) {
    int t = blockIdx.x * 256 + threadIdx.x;
    if (t < NE) {
        atomicAdd(&deg_out[src[t]], 1.0f);
        atomicAdd(&deg_in[dst[t]], 1.0f);
    }
}

__global__ __launch_bounds__(256) void k_rsqrt(float* __restrict__ d) {
    int t = blockIdx.x * 256 + threadIdx.x;
    if (t < 2 * NN) d[t] = rsqrtf(fmaxf(d[t], 1.0f));
}

// h0 = (x @ W0) * r_out ; one wave per node (8 nodes/wave serially)
__global__ __launch_bounds__(256) void k_gemm0(const float* __restrict__ x,
                                               const float* __restrict__ W0,
                                               const float* __restrict__ r_out,
                                               float* __restrict__ A) {
    __shared__ float Wl[128 * 64];  // 32 KB
    int tid = threadIdx.x;
#pragma unroll
    for (int i = 0; i < 32; ++i) Wl[i * 256 + tid] = W0[i * 256 + tid];
    __syncthreads();
    int wave = tid >> 6, lane = tid & 63;
    int base = (blockIdx.x * 4 + wave) * 8;
    for (int j = 0; j < 8; ++j) {
        int node = base + j;
        float xv0 = x[node * 128 + lane];
        float xv1 = x[node * 128 + 64 + lane];
        float acc = 0.f;
#pragma unroll 16
        for (int k = 0; k < 64; ++k) {
            acc = fmaf(__shfl(xv0, k), Wl[k * 64 + lane], acc);
            acc = fmaf(__shfl(xv1, k), Wl[(k + 64) * 64 + lane], acc);
        }
        A[node * 64 + lane] = acc * r_out[node];
    }
}

// agg[dst] += h[src], d=64, 16 threads/edge, float4 gather + 4 scalar atomics
__global__ __launch_bounds__(256) void k_scatter64(const int* __restrict__ src,
                                                   const int* __restrict__ dst,
                                                   const float* __restrict__ h,
                                                   float* __restrict__ agg) {
    int t = blockIdx.x * 256 + threadIdx.x;
    int e = t >> 4;
    int f4 = (t & 15) << 2;
    int s = src[e], d = dst[e];
    float4 v = *(const float4*)(h + (size_t)s * 64 + f4);
    float* p = agg + (size_t)d * 64 + f4;
    atomicAdd(p + 0, v.x);
    atomicAdd(p + 1, v.y);
    atomicAdd(p + 2, v.z);
    atomicAdd(p + 3, v.w);
}

// agg[dst] += h[src], d=16, 4 threads/edge
__global__ __launch_bounds__(256) void k_scatter16(const int* __restrict__ src,
                                                   const int* __restrict__ dst,
                                                   const float* __restrict__ h,
                                                   float* __restrict__ agg) {
    int t = blockIdx.x * 256 + threadIdx.x;
    int e = t >> 2;
    int f4 = (t & 3) << 2;
    int s = src[e], d = dst[e];
    float4 v = *(const float4*)(h + (size_t)s * 16 + f4);
    float* p = agg + (size_t)d * 16 + f4;
    atomicAdd(p + 0, v.x);
    atomicAdd(p + 1, v.y);
    atomicAdd(p + 2, v.z);
    atomicAdd(p + 3, v.w);
}

// A = relu(B * r_in + b0) * r_out   (layer0 epilogue + layer1 deg_out prescale)
__global__ __launch_bounds__(256) void k_post0(const float* __restrict__ B,
                                               const float* __restrict__ r_in,
                                               const float* __restrict__ r_out,
                                               const float* __restrict__ b0,
                                               float* __restrict__ A) {
    int t = blockIdx.x * 256 + threadIdx.x;
    if (t >= NN * 16) return;
    int node = t >> 4;
    int f4 = (t & 15) << 2;
    float ri = r_in[node], ro = r_out[node];
    float4 v = *(const float4*)(B + (size_t)node * 64 + f4);
    float4 b = *(const float4*)(b0 + f4);
    float4 o;
    o.x = fmaxf(fmaf(v.x, ri, b.x), 0.f) * ro;
    o.y = fmaxf(fmaf(v.y, ri, b.y), 0.f) * ro;
    o.z = fmaxf(fmaf(v.z, ri, b.z), 0.f) * ro;
    o.w = fmaxf(fmaf(v.w, ri, b.w), 0.f) * ro;
    *(float4*)(A + (size_t)node * 64 + f4) = o;
}

// z = relu((B * r_in) @ W1 + b1); C = (z @ W2) * r_out    one wave per node
__global__ __launch_bounds__(256) void k_post1(const float* __restrict__ B,
                                               const float* __restrict__ r_in,
                                               const float* __restrict__ r_out,
                                               const float* __restrict__ W1,
                                               const float* __restrict__ b1,
                                               const float* __restrict__ W2,
                                               float* __restrict__ C) {
    __shared__ float W1l[64 * 64];  // 16 KB
    __shared__ float W2l[64 * 16];  // 4 KB
    int tid = threadIdx.x;
#pragma unroll
    for (int i = 0; i < 16; ++i) W1l[i * 256 + tid] = W1[i * 256 + tid];
#pragma unroll
    for (int i = 0; i < 4; ++i) W2l[i * 256 + tid] = W2[i * 256 + tid];
    __syncthreads();
    int wave = tid >> 6, lane = tid & 63;
    float bb = b1[lane];
    int base = (blockIdx.x * 4 + wave) * 8;
    int c = lane & 15, g = lane >> 4;
    for (int j = 0; j < 8; ++j) {
        int node = base + j;
        float xv = B[(size_t)node * 64 + lane] * r_in[node];
        float z = bb;
#pragma unroll 16
        for (int k = 0; k < 64; ++k) z = fmaf(__shfl(xv, k), W1l[k * 64 + lane], z);
        z = fmaxf(z, 0.f);
        float acc = 0.f;
#pragma unroll
        for (int kk = 0; kk < 16; ++kk) {
            int k = g * 16 + kk;
            acc = fmaf(__shfl(z, k), W2l[k * 16 + c], acc);
        }
        acc += __shfl_xor(acc, 16);
        acc += __shfl_xor(acc, 32);
        if (lane < 16) C[(size_t)node * 16 + lane] = acc * r_out[node];
    }
}

// out = D * r_in + b2
__global__ __launch_bounds__(256) void k_post2(const float* __restrict__ D,
                                               const float* __restrict__ r_in,
                                               const float* __restrict__ b2,
                                               float* __restrict__ out) {
    int t = blockIdx.x * 256 + threadIdx.x;
    if (t >= NN * 4) return;
    int node = t >> 2;
    int c4 = (t & 3) << 2;
    float ri = r_in[node];
    float4 v = *(const float4*)(D + (size_t)node * 16 + c4);
    float4 b = *(const float4*)(b2 + c4);
    float4 o;
    o.x = fmaf(v.x, ri, b.x);
    o.y = fmaf(v.y, ri, b.y);
    o.z = fmaf(v.z, ri, b.z);
    o.w = fmaf(v.w, ri, b.w);
    *(float4*)(out + (size_t)node * 16 + c4) = o;
}

extern "C" void kernel_launch(void* const* d_in, const int* in_sizes, int n_in,
                              void* d_out, int out_size, void* d_ws, size_t ws_size,
                              hipStream_t stream) {
    const float* feats = (const float*)d_in[0];
    const int* src = (const int*)d_in[1];
    const int* dst = (const int*)d_in[2];
    const float* W0 = (const float*)d_in[3];
    const float* b0 = (const float*)d_in[4];
    const float* W1 = (const float*)d_in[5];
    const float* b1 = (const float*)d_in[6];
    const float* W2 = (const float*)d_in[7];
    const float* b2 = (const float*)d_in[8];
    float* out = (float*)d_out;

    float* ws = (float*)d_ws;
    float* r_out = ws;
    float* r_in = ws + NN;
    float* A = ws + 2 * NN;
    float* B = A + (size_t)NN * 64;
    float* C = B + (size_t)NN * 64;
    float* D = C + (size_t)NN * 16;

    // degrees
    hipMemsetAsync(r_out, 0, 2 * NN * sizeof(float), stream);
    k_deg<<<(NE + 255) / 256, 256, 0, stream>>>(src, dst, r_out, r_in);
    k_rsqrt<<<(2 * NN + 255) / 256, 256, 0, stream>>>(r_out);

    // layer 0 (pre-W): A = (x@W0)*r_out
    k_gemm0<<<NN / 32, 256, 0, stream>>>(feats, W0, r_out, A);
    hipMemsetAsync(B, 0, (size_t)NN * 64 * sizeof(float), stream);
    k_scatter64<<<NE * 16 / 256, 256, 0, stream>>>(src, dst, A, B);
    // epilogue 0 + layer1 prescale: A = relu(B*r_in + b0)*r_out
    k_post0<<<(NN * 16 + 255) / 256, 256, 0, stream>>>(B, r_in, r_out, b0, A);

    // layer 1 aggregation (post-W)
    hipMemsetAsync(B, 0, (size_t)NN * 64 * sizeof(float), stream);
    k_scatter64<<<NE * 16 / 256, 256, 0, stream>>>(src, dst, A, B);
    // z = relu((B*r_in)@W1 + b1); C = (z@W2)*r_out   (layer2 pre-W fused)
    k_post1<<<NN / 32, 256, 0, stream>>>(B, r_in, r_out, W1, b1, W2, C);

    // layer 2 aggregation
    hipMemsetAsync(D, 0, (size_t)NN * 16 * sizeof(float), stream);
    k_scatter16<<<NE * 4 / 256, 256, 0, stream>>>(src, dst, C, D);
    k_post2<<<(NN * 4 + 255) / 256, 256, 0, stream>>>(D, r_in, b2, out);
}

// Round 2
// 870.829 us; speedup vs baseline: 4.1528x; 4.1528x over previous
//
#include <hip/hip_runtime.h>

#define NN 100000
#define NE 1600000
#define NB 391  // ceil(NN/256)

// ---------------- CSR build ----------------

__global__ __launch_bounds__(256) void k_count(const int* __restrict__ src,
                                               const int* __restrict__ dst,
                                               int* __restrict__ cnt_out,
                                               int* __restrict__ cnt_in) {
    int t = blockIdx.x * 256 + threadIdx.x;
    if (t < NE) {
        atomicAdd(&cnt_out[src[t]], 1);
        atomicAdd(&cnt_in[dst[t]], 1);
    }
}

__global__ __launch_bounds__(256) void k_scan1(const int* __restrict__ cnt,
                                               int* __restrict__ bsum) {
    __shared__ int tmp[256];
    int t = threadIdx.x;
    int i = blockIdx.x * 256 + t;
    int v = (i < NN) ? cnt[i] : 0;
    tmp[t] = v;
    __syncthreads();
    for (int off = 1; off < 256; off <<= 1) {
        int u = (t >= off) ? tmp[t - off] : 0;
        __syncthreads();
        tmp[t] += u;
        __syncthreads();
    }
    if (t == 255) bsum[blockIdx.x] = tmp[255];
}

__global__ __launch_bounds__(512) void k_scan2(int* __restrict__ bsum,
                                               int* __restrict__ row_start) {
    __shared__ int tmp[512];
    int t = threadIdx.x;
    int v = (t < NB) ? bsum[t] : 0;
    tmp[t] = v;
    __syncthreads();
    for (int off = 1; off < 512; off <<= 1) {
        int u = (t >= off) ? tmp[t - off] : 0;
        __syncthreads();
        tmp[t] += u;
        __syncthreads();
    }
    if (t < NB) bsum[t] = tmp[t] - v;  // exclusive
    if (t == 0) row_start[NN] = NE;
}

__global__ __launch_bounds__(256) void k_scan3(const int* __restrict__ cnt,
                                               const int* __restrict__ bsum,
                                               int* __restrict__ row_start,
                                               int* __restrict__ cursor) {
    __shared__ int tmp[256];
    int t = threadIdx.x;
    int i = blockIdx.x * 256 + t;
    int v = (i < NN) ? cnt[i] : 0;
    tmp[t] = v;
    __syncthreads();
    for (int off = 1; off < 256; off <<= 1) {
        int u = (t >= off) ? tmp[t - off] : 0;
        __syncthreads();
        tmp[t] += u;
        __syncthreads();
    }
    if (i < NN) {
        int row = bsum[blockIdx.x] + tmp[t] - v;
        row_start[i] = row;
        cursor[i] = row;
    }
}

__global__ __launch_bounds__(256) void k_fill(const int* __restrict__ src,
                                              const int* __restrict__ dst,
                                              int* __restrict__ cursor,
                                              int* __restrict__ csr) {
    int t = blockIdx.x * 256 + threadIdx.x;
    if (t < NE) {
        int pos = atomicAdd(&cursor[dst[t]], 1);
        csr[pos] = src[t];
    }
}

__global__ __launch_bounds__(256) void k_rsqrt(const int* __restrict__ cnt_out,
                                               const int* __restrict__ cnt_in,
                                               float* __restrict__ r_out,
                                               float* __restrict__ r_in) {
    int t = blockIdx.x * 256 + threadIdx.x;
    if (t < NN) {
        r_out[t] = rsqrtf((float)max(cnt_out[t], 1));
        r_in[t] = rsqrtf((float)max(cnt_in[t], 1));
    }
}

// ---------------- dense + gather ----------------

// h0 = (x @ W0) * r_out ; one wave per 8 nodes
__global__ __launch_bounds__(256) void k_gemm0(const float* __restrict__ x,
                                               const float* __restrict__ W0,
                                               const float* __restrict__ r_out,
                                               float* __restrict__ A) {
    __shared__ float Wl[128 * 64];  // 32 KB
    int tid = threadIdx.x;
#pragma unroll
    for (int i = 0; i < 32; ++i) Wl[i * 256 + tid] = W0[i * 256 + tid];
    __syncthreads();
    int wave = tid >> 6, lane = tid & 63;
    int base = (blockIdx.x * 4 + wave) * 8;
    for (int j = 0; j < 8; ++j) {
        int node = base + j;
        float xv0 = x[node * 128 + lane];
        float xv1 = x[node * 128 + 64 + lane];
        float acc = 0.f;
#pragma unroll 16
        for (int k = 0; k < 64; ++k) {
            acc = fmaf(__shfl(xv0, k), Wl[k * 64 + lane], acc);
            acc = fmaf(__shfl(xv1, k), Wl[(k + 64) * 64 + lane], acc);
        }
        A[node * 64 + lane] = acc * r_out[node];
    }
}

// layer0 aggregation: B[n] = relu((sum_{s in N(n)} A[s]) * r_in[n] + b0) * r_out[n]
__global__ __launch_bounds__(256) void k_gather0(const int* __restrict__ row_start,
                                                 const int* __restrict__ csr,
                                                 const float* __restrict__ A,
                                                 const float* __restrict__ r_in,
                                                 const float* __restrict__ r_out,
                                                 const float* __restrict__ b0,
                                                 float* __restrict__ B) {
    int tid = threadIdx.x;
    int wave = tid >> 6, lane = tid & 63;
    int n = blockIdx.x * 4 + wave;
    int jb = row_start[n], je = row_start[n + 1];
    float acc0 = 0.f, acc1 = 0.f;
    int j = jb;
    for (; j + 1 < je; j += 2) {
        int s0 = csr[j], s1 = csr[j + 1];
        acc0 += A[s0 * 64 + lane];
        acc1 += A[s1 * 64 + lane];
    }
    if (j < je) acc0 += A[csr[j] * 64 + lane];
    float agg = acc0 + acc1;
    B[n * 64 + lane] = fmaxf(fmaf(agg, r_in[n], b0[lane]), 0.f) * r_out[n];
}

// layer1 aggregation + full dense stack:
//   agg = sum B[s]; z = relu(agg*r_in @ W1 + b1); C[n] = (z @ W2) * r_out[n]
__global__ __launch_bounds__(256) void k_gather_mlp(const int* __restrict__ row_start,
                                                    const int* __restrict__ csr,
                                                    const float* __restrict__ B,
                                                    const float* __restrict__ r_in,
                                                    const float* __restrict__ r_out,
                                                    const float* __restrict__ W1,
                                                    const float* __restrict__ b1,
                                                    const float* __restrict__ W2,
                                                    float* __restrict__ C) {
    __shared__ float W1l[64 * 64];  // 16 KB
    __shared__ float W2l[64 * 16];  // 4 KB
    int tid = threadIdx.x;
#pragma unroll
    for (int i = 0; i < 16; ++i) W1l[i * 256 + tid] = W1[i * 256 + tid];
#pragma unroll
    for (int i = 0; i < 4; ++i) W2l[i * 256 + tid] = W2[i * 256 + tid];
    __syncthreads();
    int wave = tid >> 6, lane = tid & 63;
    int n = blockIdx.x * 4 + wave;
    int jb = row_start[n], je = row_start[n + 1];
    float acc0 = 0.f, acc1 = 0.f;
    int j = jb;
    for (; j + 1 < je; j += 2) {
        int s0 = csr[j], s1 = csr[j + 1];
        acc0 += B[s0 * 64 + lane];
        acc1 += B[s1 * 64 + lane];
    }
    if (j < je) acc0 += B[csr[j] * 64 + lane];
    float xv = (acc0 + acc1) * r_in[n];
    float z = b1[lane];
#pragma unroll 16
    for (int k = 0; k < 64; ++k) z = fmaf(__shfl(xv, k), W1l[k * 64 + lane], z);
    z = fmaxf(z, 0.f);
    int c = lane & 15, g = lane >> 4;
    float acc = 0.f;
#pragma unroll
    for (int kk = 0; kk < 16; ++kk) {
        int k = g * 16 + kk;
        acc = fmaf(__shfl(z, k), W2l[k * 16 + c], acc);
    }
    acc += __shfl_xor(acc, 16);
    acc += __shfl_xor(acc, 32);
    if (lane < 16) C[n * 16 + lane] = acc * r_out[n];
}

// layer2 aggregation (d=16): out[n] = (sum C[s]) * r_in[n] + b2
// 4 nodes per wave: lane = (sub=lane>>4, f=lane&15)
__global__ __launch_bounds__(256) void k_gather16(const int* __restrict__ row_start,
                                                  const int* __restrict__ csr,
                                                  const float* __restrict__ C,
                                                  const float* __restrict__ r_in,
                                                  const float* __restrict__ b2,
                                                  float* __restrict__ out) {
    int tid = threadIdx.x;
    int wave = tid >> 6, lane = tid & 63;
    int f = lane & 15, sub = lane >> 4;
    int n = (blockIdx.x * 4 + wave) * 4 + sub;
    int jb = row_start[n], je = row_start[n + 1];
    float acc = 0.f;
    for (int j = jb; j < je; ++j) {
        int s = csr[j];
        acc += C[s * 16 + f];
    }
    out[n * 16 + f] = fmaf(acc, r_in[n], b2[f]);
}

extern "C" void kernel_launch(void* const* d_in, const int* in_sizes, int n_in,
                              void* d_out, int out_size, void* d_ws, size_t ws_size,
                              hipStream_t stream) {
    const float* feats = (const float*)d_in[0];
    const int* src = (const int*)d_in[1];
    const int* dst = (const int*)d_in[2];
    const float* W0 = (const float*)d_in[3];
    const float* b0 = (const float*)d_in[4];
    const float* W1 = (const float*)d_in[5];
    const float* b1 = (const float*)d_in[6];
    const float* W2 = (const float*)d_in[7];
    const float* b2 = (const float*)d_in[8];
    float* out = (float*)d_out;

    // ws layout (elements):
    // r_out[NN] | r_in[NN] | row_start[NN+1 pad to NN+16] | csr[NE] | A[64NN] | B[64NN]
    // transient ints (cnt_out, cnt_in, cursor, bsum) alias B; C[16NN] aliases A.
    float* ws = (float*)d_ws;
    float* r_out = ws;
    float* r_in = ws + NN;
    int* row_start = (int*)(ws + 2 * NN);            // NN+1
    int* csr = (int*)(ws + 3 * NN + 16);             // NE
    float* A = ws + 3 * NN + 16 + NE;                // 64*NN
    float* B = A + (size_t)64 * NN;                  // 64*NN
    int* cnt_out = (int*)B;                          // NN (transient)
    int* cnt_in = cnt_out + NN;                      // NN (transient)
    int* cursor = cnt_in + NN;                       // NN (transient)
    int* bsum = cursor + NN;                         // 512 (transient)
    float* C = A;                                    // 16*NN, alias A (dead by then)

    // CSR build + degree norms
    hipMemsetAsync(cnt_out, 0, 2 * NN * sizeof(int), stream);
    k_count<<<(NE + 255) / 256, 256, 0, stream>>>(src, dst, cnt_out, cnt_in);
    k_scan1<<<NB, 256, 0, stream>>>(cnt_in, bsum);
    k_scan2<<<1, 512, 0, stream>>>(bsum, row_start);
    k_scan3<<<NB, 256, 0, stream>>>(cnt_in, bsum, row_start, cursor);
    k_rsqrt<<<NB, 256, 0, stream>>>(cnt_out, cnt_in, r_out, r_in);
    k_fill<<<(NE + 255) / 256, 256, 0, stream>>>(src, dst, cursor, csr);

    // layer 0: A = (x@W0)*r_out, then gathered into B with fused epilogue
    k_gemm0<<<NN / 32, 256, 0, stream>>>(feats, W0, r_out, A);
    k_gather0<<<NN / 4, 256, 0, stream>>>(row_start, csr, A, r_in, r_out, b0, B);

    // layer 1 gather + dense stack (W1, relu, W2, layer2 prescale) -> C
    k_gather_mlp<<<NN / 4, 256, 0, stream>>>(row_start, csr, B, r_in, r_out, W1, b1, W2, C);

    // layer 2 gather (d=16) + final bias -> out
    k_gather16<<<NN / 16, 256, 0, stream>>>(row_start, csr, C, r_in, b2, out);
}

// Round 3
// 552.030 us; speedup vs baseline: 6.5511x; 1.5775x over previous
//
#include <hip/hip_runtime.h>

#define NN 100000
#define NE 1600000
#define NB 391  // ceil(NN/256)

// ---------------- CSR build ----------------

__global__ __launch_bounds__(256) void k_count(const int* __restrict__ src,
                                               const int* __restrict__ dst,
                                               int* __restrict__ cnt_out,
                                               int* __restrict__ cnt_in) {
    int t = blockIdx.x * 256 + threadIdx.x;
    if (t < NE) {
        atomicAdd(&cnt_out[src[t]], 1);
        atomicAdd(&cnt_in[dst[t]], 1);
    }
}

__global__ __launch_bounds__(256) void k_scan1(const int* __restrict__ cnt,
                                               int* __restrict__ bsum) {
    __shared__ int tmp[256];
    int t = threadIdx.x;
    int i = blockIdx.x * 256 + t;
    int v = (i < NN) ? cnt[i] : 0;
    tmp[t] = v;
    __syncthreads();
    for (int off = 1; off < 256; off <<= 1) {
        int u = (t >= off) ? tmp[t - off] : 0;
        __syncthreads();
        tmp[t] += u;
        __syncthreads();
    }
    if (t == 255) bsum[blockIdx.x] = tmp[255];
}

__global__ __launch_bounds__(512) void k_scan2(int* __restrict__ bsum,
                                               int* __restrict__ row_start) {
    __shared__ int tmp[512];
    int t = threadIdx.x;
    int v = (t < NB) ? bsum[t] : 0;
    tmp[t] = v;
    __syncthreads();
    for (int off = 1; off < 512; off <<= 1) {
        int u = (t >= off) ? tmp[t - off] : 0;
        __syncthreads();
        tmp[t] += u;
        __syncthreads();
    }
    if (t < NB) bsum[t] = tmp[t] - v;  // exclusive
    if (t == 0) row_start[NN] = NE;
}

__global__ __launch_bounds__(256) void k_scan3(const int* __restrict__ cnt,
                                               const int* __restrict__ bsum,
                                               int* __restrict__ row_start,
                                               int* __restrict__ cursor) {
    __shared__ int tmp[256];
    int t = threadIdx.x;
    int i = blockIdx.x * 256 + t;
    int v = (i < NN) ? cnt[i] : 0;
    tmp[t] = v;
    __syncthreads();
    for (int off = 1; off < 256; off <<= 1) {
        int u = (t >= off) ? tmp[t - off] : 0;
        __syncthreads();
        tmp[t] += u;
        __syncthreads();
    }
    if (i < NN) {
        int row = bsum[blockIdx.x] + tmp[t] - v;
        row_start[i] = row;
        cursor[i] = row;
    }
}

__global__ __launch_bounds__(256) void k_fill(const int* __restrict__ src,
                                              const int* __restrict__ dst,
                                              int* __restrict__ cursor,
                                              int* __restrict__ csr) {
    int t = blockIdx.x * 256 + threadIdx.x;
    if (t < NE) {
        int pos = atomicAdd(&cursor[dst[t]], 1);
        csr[pos] = src[t];
    }
}

__global__ __launch_bounds__(256) void k_rsqrt(const int* __restrict__ cnt_out,
                                               const int* __restrict__ cnt_in,
                                               float* __restrict__ r_out,
                                               float* __restrict__ r_in) {
    int t = blockIdx.x * 256 + threadIdx.x;
    if (t < NN) {
        r_out[t] = rsqrtf((float)max(cnt_out[t], 1));
        r_in[t] = rsqrtf((float)max(cnt_in[t], 1));
    }
}

// ---------------- dense GEMMs (register-blocked) ----------------

// A = (x @ W0) * r_out.  64 nodes/block, thread = 4m x 4n, K=128 in two halves.
__global__ __launch_bounds__(256) void k_gemm0(const float* __restrict__ x,
                                               const float* __restrict__ W0,
                                               const float* __restrict__ r_out,
                                               float* __restrict__ A) {
    __shared__ float xl[64 * 129];  // 33.0 KB, +1 pad -> 2-way (free) on reads
    __shared__ float wl[64 * 64];   // 16.4 KB, one K-half at a time
    int tid = threadIdx.x;
    int m0 = blockIdx.x * 64;

    // stage x tile: 64x128 floats = 2048 float4, 8 per thread
#pragma unroll
    for (int i = 0; i < 8; ++i) {
        int idx = i * 256 + tid;
        int m = idx >> 5, kc = idx & 31;
        int gm = min(m0 + m, NN - 1);
        float4 v = *(const float4*)&x[(size_t)gm * 128 + kc * 4];
        float* p = &xl[m * 129 + kc * 4];
        p[0] = v.x; p[1] = v.y; p[2] = v.z; p[3] = v.w;
    }

    int tn = tid & 15, tm = tid >> 4;
    float acc[4][4] = {};
    const float4* W4 = (const float4*)W0;
    float4* wl4 = (float4*)wl;

    for (int h = 0; h < 2; ++h) {
        __syncthreads();
        // stage W half: 64x64 floats = 1024 float4, 4 per thread
#pragma unroll
        for (int i = 0; i < 4; ++i) wl4[i * 256 + tid] = W4[h * 1024 + i * 256 + tid];
        __syncthreads();
#pragma unroll 4
        for (int k = 0; k < 64; ++k) {
            int kk = h * 64 + k;
            float4 wv = *(const float4*)&wl[k * 64 + tn * 4];
            float xv[4];
#pragma unroll
            for (int i = 0; i < 4; ++i) xv[i] = xl[(tm * 4 + i) * 129 + kk];
#pragma unroll
            for (int i = 0; i < 4; ++i) {
                acc[i][0] = fmaf(xv[i], wv.x, acc[i][0]);
                acc[i][1] = fmaf(xv[i], wv.y, acc[i][1]);
                acc[i][2] = fmaf(xv[i], wv.z, acc[i][2]);
                acc[i][3] = fmaf(xv[i], wv.w, acc[i][3]);
            }
        }
    }
#pragma unroll
    for (int i = 0; i < 4; ++i) {
        int m = m0 + tm * 4 + i;
        if (m < NN) {
            float ro = r_out[m];
            float4 o = {acc[i][0] * ro, acc[i][1] * ro, acc[i][2] * ro, acc[i][3] * ro};
            *(float4*)&A[(size_t)m * 64 + tn * 4] = o;
        }
    }
}

// C = (relu(G @ W1 + b1) @ W2) * r_out.  64 nodes/block.
__global__ __launch_bounds__(256) void k_mlp(const float* __restrict__ G,
                                             const float* __restrict__ W1,
                                             const float* __restrict__ b1,
                                             const float* __restrict__ W2,
                                             const float* __restrict__ r_out,
                                             float* __restrict__ C) {
    __shared__ float gl[64 * 65];   // 16.6 KB (also holds z after relu)
    __shared__ float w1l[64 * 64];  // 16.4 KB
    __shared__ float w2l[64 * 16];  // 4 KB
    int tid = threadIdx.x;
    int m0 = blockIdx.x * 64;

    // stage G tile: 64x64 = 1024 float4, 4/thread
#pragma unroll
    for (int i = 0; i < 4; ++i) {
        int idx = i * 256 + tid;
        int m = idx >> 4, kc = idx & 15;
        int gm = min(m0 + m, NN - 1);
        float4 v = *(const float4*)&G[(size_t)gm * 64 + kc * 4];
        float* p = &gl[m * 65 + kc * 4];
        p[0] = v.x; p[1] = v.y; p[2] = v.z; p[3] = v.w;
    }
    float4* w1l4 = (float4*)w1l;
    const float4* W1_4 = (const float4*)W1;
#pragma unroll
    for (int i = 0; i < 4; ++i) w1l4[i * 256 + tid] = W1_4[i * 256 + tid];
    ((float4*)w2l)[tid] = ((const float4*)W2)[tid];
    __syncthreads();

    // GEMM1: z = relu(G @ W1 + b1), thread = 4m x 4n
    int tn = tid & 15, tm = tid >> 4;
    float acc[4][4] = {};
#pragma unroll 4
    for (int k = 0; k < 64; ++k) {
        float4 wv = *(const float4*)&w1l[k * 64 + tn * 4];
        float xv[4];
#pragma unroll
        for (int i = 0; i < 4; ++i) xv[i] = gl[(tm * 4 + i) * 65 + k];
#pragma unroll
        for (int i = 0; i < 4; ++i) {
            acc[i][0] = fmaf(xv[i], wv.x, acc[i][0]);
            acc[i][1] = fmaf(xv[i], wv.y, acc[i][1]);
            acc[i][2] = fmaf(xv[i], wv.z, acc[i][2]);
            acc[i][3] = fmaf(xv[i], wv.w, acc[i][3]);
        }
    }
    float4 bb = *(const float4*)&b1[tn * 4];
    __syncthreads();  // all reads of gl done
#pragma unroll
    for (int i = 0; i < 4; ++i) {
        gl[(tm * 4 + i) * 65 + tn * 4 + 0] = fmaxf(acc[i][0] + bb.x, 0.f);
        gl[(tm * 4 + i) * 65 + tn * 4 + 1] = fmaxf(acc[i][1] + bb.y, 0.f);
        gl[(tm * 4 + i) * 65 + tn * 4 + 2] = fmaxf(acc[i][2] + bb.z, 0.f);
        gl[(tm * 4 + i) * 65 + tn * 4 + 3] = fmaxf(acc[i][3] + bb.w, 0.f);
    }
    __syncthreads();

    // GEMM2: C = (z @ W2) * r_out, thread = 1m x 4n
    int m = tid >> 2, n0 = (tid & 3) * 4;
    float a2[4] = {};
#pragma unroll 8
    for (int k = 0; k < 64; ++k) {
        float zv = gl[m * 65 + k];
        float4 wv = *(const float4*)&w2l[k * 16 + n0];
        a2[0] = fmaf(zv, wv.x, a2[0]);
        a2[1] = fmaf(zv, wv.y, a2[1]);
        a2[2] = fmaf(zv, wv.z, a2[2]);
        a2[3] = fmaf(zv, wv.w, a2[3]);
    }
    int node = m0 + m;
    if (node < NN) {
        float ro = r_out[node];
        float4 o = {a2[0] * ro, a2[1] * ro, a2[2] * ro, a2[3] * ro};
        *(float4*)&C[(size_t)node * 16 + n0] = o;
    }
}

// ---------------- gathers ----------------

// d=64 gather, 1 node/wave, 4 edges in flight (16 lanes x float4 each), unroll x2.
// MODE 0: out = relu(agg*r_in + bias)*r_out   (layer0 epilogue + layer1 prescale)
// MODE 1: out = agg*r_in                      (layer1 agg, feeds k_mlp)
template <int MODE>
__global__ __launch_bounds__(256) void k_gather64(const int* __restrict__ row_start,
                                                  const int* __restrict__ csr,
                                                  const float* __restrict__ h,
                                                  const float* __restrict__ r_in,
                                                  const float* __restrict__ r_out,
                                                  const float* __restrict__ bias,
                                                  float* __restrict__ outb) {
    int tid = threadIdx.x;
    int wave = tid >> 6, lane = tid & 63;
    int n = blockIdx.x * 4 + wave;
    int jb = row_start[n], je = row_start[n + 1];
    int g = lane >> 4, f = lane & 15;
    float4 a0 = {0, 0, 0, 0}, a1 = {0, 0, 0, 0};
    for (int j = jb; j < je; j += 8) {
        int i0 = j + g, i1 = j + 4 + g;
        int s0 = csr[min(i0, je - 1)];
        int s1 = csr[min(i1, je - 1)];
        float4 v0 = *(const float4*)&h[(size_t)s0 * 64 + f * 4];
        float4 v1 = *(const float4*)&h[(size_t)s1 * 64 + f * 4];
        float w0 = (i0 < je) ? 1.f : 0.f;
        float w1 = (i1 < je) ? 1.f : 0.f;
        a0.x = fmaf(w0, v0.x, a0.x); a0.y = fmaf(w0, v0.y, a0.y);
        a0.z = fmaf(w0, v0.z, a0.z); a0.w = fmaf(w0, v0.w, a0.w);
        a1.x = fmaf(w1, v1.x, a1.x); a1.y = fmaf(w1, v1.y, a1.y);
        a1.z = fmaf(w1, v1.z, a1.z); a1.w = fmaf(w1, v1.w, a1.w);
    }
    a0.x += a1.x; a0.y += a1.y; a0.z += a1.z; a0.w += a1.w;
    a0.x += __shfl_xor(a0.x, 16); a0.y += __shfl_xor(a0.y, 16);
    a0.z += __shfl_xor(a0.z, 16); a0.w += __shfl_xor(a0.w, 16);
    a0.x += __shfl_xor(a0.x, 32); a0.y += __shfl_xor(a0.y, 32);
    a0.z += __shfl_xor(a0.z, 32); a0.w += __shfl_xor(a0.w, 32);
    if (g == 0) {
        float ri = r_in[n];
        float4 o;
        if (MODE == 0) {
            float ro = r_out[n];
            float4 bb = *(const float4*)&bias[f * 4];
            o.x = fmaxf(fmaf(a0.x, ri, bb.x), 0.f) * ro;
            o.y = fmaxf(fmaf(a0.y, ri, bb.y), 0.f) * ro;
            o.z = fmaxf(fmaf(a0.z, ri, bb.z), 0.f) * ro;
            o.w = fmaxf(fmaf(a0.w, ri, bb.w), 0.f) * ro;
        } else {
            o.x = a0.x * ri; o.y = a0.y * ri; o.z = a0.z * ri; o.w = a0.w * ri;
        }
        *(float4*)&outb[(size_t)n * 64 + f * 4] = o;
    }
}

// d=16 gather: 1 node/wave, 16 edges in flight (4 lanes x float4 each).
// out = agg*r_in + b2
__global__ __launch_bounds__(256) void k_gather16(const int* __restrict__ row_start,
                                                  const int* __restrict__ csr,
                                                  const float* __restrict__ C,
                                                  const float* __restrict__ r_in,
                                                  const float* __restrict__ b2,
                                                  float* __restrict__ out) {
    int tid = threadIdx.x;
    int wave = tid >> 6, lane = tid & 63;
    int n = blockIdx.x * 4 + wave;
    int jb = row_start[n], je = row_start[n + 1];
    int g = lane >> 2, f = lane & 3;
    float4 acc = {0, 0, 0, 0};
    for (int j = jb; j < je; j += 16) {
        int i0 = j + g;
        int s = csr[min(i0, je - 1)];
        float4 v = *(const float4*)&C[(size_t)s * 16 + f * 4];
        float w = (i0 < je) ? 1.f : 0.f;
        acc.x = fmaf(w, v.x, acc.x); acc.y = fmaf(w, v.y, acc.y);
        acc.z = fmaf(w, v.z, acc.z); acc.w = fmaf(w, v.w, acc.w);
    }
#pragma unroll
    for (int m = 4; m <= 32; m <<= 1) {
        acc.x += __shfl_xor(acc.x, m); acc.y += __shfl_xor(acc.y, m);
        acc.z += __shfl_xor(acc.z, m); acc.w += __shfl_xor(acc.w, m);
    }
    if (g == 0) {
        float ri = r_in[n];
        float4 bb = *(const float4*)&b2[f * 4];
        float4 o;
        o.x = fmaf(acc.x, ri, bb.x); o.y = fmaf(acc.y, ri, bb.y);
        o.z = fmaf(acc.z, ri, bb.z); o.w = fmaf(acc.w, ri, bb.w);
        *(float4*)&out[(size_t)n * 16 + f * 4] = o;
    }
}

extern "C" void kernel_launch(void* const* d_in, const int* in_sizes, int n_in,
                              void* d_out, int out_size, void* d_ws, size_t ws_size,
                              hipStream_t stream) {
    const float* feats = (const float*)d_in[0];
    const int* src = (const int*)d_in[1];
    const int* dst = (const int*)d_in[2];
    const float* W0 = (const float*)d_in[3];
    const float* b0 = (const float*)d_in[4];
    const float* W1 = (const float*)d_in[5];
    const float* b1 = (const float*)d_in[6];
    const float* W2 = (const float*)d_in[7];
    const float* b2 = (const float*)d_in[8];
    float* out = (float*)d_out;

    // ws layout (floats/ints):
    // r_out[NN] | r_in[NN] | row_start[NN+16] | csr[NE+16] | A[64NN] | B[64NN]
    // transient: cnt_out/cnt_in/cursor/bsum alias A (dead before gemm0 writes A)
    // G aliases A (A dead after gather0); C aliases B (B dead after gather1)
    float* ws = (float*)d_ws;
    float* r_out = ws;
    float* r_in = ws + NN;
    int* row_start = (int*)(ws + 2 * NN);         // NN+1 (padded 16)
    int* csr = (int*)(ws + 3 * NN + 16);          // NE (+pad)
    float* A = ws + 3 * NN + 32 + NE;             // 64*NN
    float* B = A + (size_t)64 * NN;               // 64*NN
    int* cnt_out = (int*)A;
    int* cnt_in = cnt_out + NN;
    int* cursor = cnt_in + NN;
    int* bsum = cursor + NN;
    float* G = A;  // layer1 agg (A dead by then)
    float* C = B;  // layer2 pre-agg, 16*NN (B dead by then)

    // CSR build + degree norms
    hipMemsetAsync(cnt_out, 0, 2 * NN * sizeof(int), stream);
    k_count<<<(NE + 255) / 256, 256, 0, stream>>>(src, dst, cnt_out, cnt_in);
    k_scan1<<<NB, 256, 0, stream>>>(cnt_in, bsum);
    k_scan2<<<1, 512, 0, stream>>>(bsum, row_start);
    k_scan3<<<NB, 256, 0, stream>>>(cnt_in, bsum, row_start, cursor);
    k_rsqrt<<<NB, 256, 0, stream>>>(cnt_out, cnt_in, r_out, r_in);
    k_fill<<<(NE + 255) / 256, 256, 0, stream>>>(src, dst, cursor, csr);

    // layer 0: A = (x@W0)*r_out ; B = relu(agg(A)*r_in + b0)*r_out
    k_gemm0<<<(NN + 63) / 64, 256, 0, stream>>>(feats, W0, r_out, A);
    k_gather64<0><<<NN / 4, 256, 0, stream>>>(row_start, csr, A, r_in, r_out, b0, B);

    // layer 1: G = agg(B)*r_in ; C = (relu(G@W1+b1)@W2)*r_out
    k_gather64<1><<<NN / 4, 256, 0, stream>>>(row_start, csr, B, r_in, r_out, b0, G);
    k_mlp<<<(NN + 63) / 64, 256, 0, stream>>>(G, W1, b1, W2, r_out, C);

    // layer 2: out = agg(C)*r_in + b2
    k_gather16<<<NN / 4, 256, 0, stream>>>(row_start, csr, C, r_in, b2, out);
}